// Round 11
// baseline (271.387 us; speedup 1.0000x reference)
//
#include <hip/hip_runtime.h>
#include <math.h>

#define EPS 1e-9f

// P[i]: circle i<Nc -> (x, y, 0.5*radius, 0)   [radius PRE-HALVED]
//       box        -> (x, y, half.x, half.y)   [unscaled]
// Also seeds out with base positions (collide atomically adds corrections).
__global__ void prep(const float2* __restrict__ cpos,
                     const float*  __restrict__ crad,
                     const float2* __restrict__ apos,
                     const float2* __restrict__ ahalf,
                     float4* __restrict__ P,
                     float2* __restrict__ out,
                     int Nc, int Ntot) {
    int i = blockIdx.x * blockDim.x + threadIdx.x;
    if (i >= Ntot) return;
    if (i < Nc) {
        const float2 p = cpos[i];
        P[i]   = make_float4(p.x, p.y, 0.5f * crad[i], 0.0f);
        out[i] = p;
    } else {
        const float2 a = apos[i - Nc];
        const float2 h = ahalf[i - Nc];
        P[i]   = make_float4(a.x, a.y, h.x, h.y);
        out[i] = a;
    }
}

__device__ __forceinline__ int tri_off(int I) { return I * (193 - I) / 2; }  // 96 tiles

// Symmetric tile-pair kernel. Forces computed in q-minus-p orientation so the
// J-side force needs no negation: scatter +fJ via LDS ATOMICS (SoA float
// arrays, 2-way bank aliasing = free; hardware-serialized so the cross-lane
// accumulation cannot be broken by compiler reordering — the R10 failure mode),
// I-side accumulates ax -= fJ. Algebra: 0.5*pen/dist = fma(Rhalf, rsq, -0.5).
__global__ __launch_bounds__(256)
void collide(const float4* __restrict__ P,
             float* __restrict__ out,
             int Nc) {
    const int lane = threadIdx.x & 63;
    const int w    = threadIdx.x >> 6;
    const int t    = blockIdx.x * 4 + w;          // tile-pair id 0..4655 (uniform)

    // triangular decode t -> (I, J), I <= J  (37249 - 8t is exact in f32)
    int I = (int)((193.0f - sqrtf((float)(37249 - 8 * t))) * 0.5f);
    while (tri_off(I + 1) <= t) ++I;
    while (tri_off(I) > t) --I;
    const int J = I + (t - tri_off(I));

    const int tileC  = Nc >> 6;                   // 64 circle tiles
    const bool bodyC = I < tileC;                 // uniform
    const bool partC = J < tileC;                 // uniform (I<=J: partC => bodyC)

    __shared__ float4 Jd[4][128];
    __shared__ float  FJx[4][128];
    __shared__ float  FJy[4][128];

    {   // stage J tile doubled; zero FJ
        const float4 q = P[(J << 6) + lane];
        Jd[w][lane]       = q;
        Jd[w][lane + 64]  = q;
        FJx[w][lane]      = 0.0f;  FJx[w][lane + 64] = 0.0f;
        FJy[w][lane]      = 0.0f;  FJy[w][lane + 64] = 0.0f;
    }
    __syncthreads();                              // ordering hygiene for staging

    const float4 me = P[(I << 6) + lane];
    float ax = 0.0f, ay = 0.0f;

    if (I != J) {
        if (partC) {                        // CC (both circle tiles)
            const float px = me.x, py = me.y, rih = me.z;
            #pragma unroll 8
            for (int m = 0; m < 64; ++m) {
                const int slot = lane + m;        // doubled arrays: no wrap
                const float4 q = Jd[w][slot];
                const float dx = q.x - px, dy = q.y - py;       // q - p
                const float d2 = fmaf(dx, dx, dy * dy);
                const float r  = __builtin_amdgcn_rsqf(d2);
                const float s  = fmaxf(fmaf(rih + q.z, r, -0.5f), 0.0f);
                const float fJx = s * dx, fJy = s * dy;         // force on J body
                ax -= fJx; ay -= fJy;                           // equal & opposite on I
                atomicAdd(&FJx[w][slot], fJx);
                atomicAdd(&FJy[w][slot], fJy);
            }
        } else if (bodyC) {                 // CB: I circle tile, J box tile
            const float px = me.x, py = me.y, rih = me.z;
            #pragma unroll 8
            for (int m = 0; m < 64; ++m) {
                const int slot = lane + m;
                const float4 q = Jd[w][slot];
                const float rx = q.x - px, ry = q.y - py;       // box - circle
                const float cx = fminf(fmaxf(rx, -q.z), q.z);   // clamp (odd fn: exact)
                const float cy = fminf(fmaxf(ry, -q.w), q.w);
                const float dx = rx - cx, dy = ry - cy;         // = -(circle diff)
                const float d2 = fmaf(dx, dx, dy * dy);
                const float r  = __builtin_amdgcn_rsqf(d2);
                float s = fmaxf(fmaf(rih, r, -0.5f), 0.0f);
                s = (d2 > EPS) ? s : 0.0f;                      // center-inside-box guard
                const float fJx = s * dx, fJy = s * dy;         // force on box
                ax -= fJx; ay -= fJy;                           // push on circle
                atomicAdd(&FJx[w][slot], fJx);
                atomicAdd(&FJy[w][slot], fJy);
            }
        } else {                            // BB (both box tiles)
            const float bx = me.x, by = me.y, hx = me.z, hy = me.w;
            #pragma unroll 8
            for (int m = 0; m < 64; ++m) {
                const int slot = lane + m;
                const float4 q = Jd[w][slot];
                const float dqx = q.x - bx, dqy = q.y - by;     // q - me
                const float ovx = (hx + q.z) - fabsf(dqx);
                const float ovy = (hy + q.w) - fabsf(dqy);
                const bool hit = fminf(ovx, ovy) > 0.0f;
                const bool ux  = ovx <= ovy;
                const float fJx = (hit && ux)  ? copysignf(0.5f * ovx, dqx) : 0.0f;
                const float fJy = (hit && !ux) ? copysignf(0.5f * ovy, dqy) : 0.0f;
                ax -= fJx; ay -= fJy;
                atomicAdd(&FJx[w][slot], fJx);
                atomicAdd(&FJy[w][slot], fJy);
            }
        }
        // flush J side (combine the two doubled halves)
        const float gx = FJx[w][lane] + FJx[w][lane + 64];
        const float gy = FJy[w][lane] + FJy[w][lane + 64];
        atomicAdd(&out[(((J << 6) + lane) << 1)],     gx);
        atomicAdd(&out[(((J << 6) + lane) << 1) + 1], gy);
    } else {
        // diagonal: gather k=1..63 (rotation never self-pairs -> no guards for CC)
        if (bodyC) {                        // CC diag
            const float px = me.x, py = me.y, rih = me.z;
            #pragma unroll 7
            for (int k = 1; k < 64; ++k) {
                const float4 q = Jd[w][lane + k];
                const float dx = px - q.x, dy = py - q.y;       // p - q (I side)
                const float d2 = fmaf(dx, dx, dy * dy);
                const float r  = __builtin_amdgcn_rsqf(d2);
                const float s  = fmaxf(fmaf(rih + q.z, r, -0.5f), 0.0f);
                ax = fmaf(s, dx, ax); ay = fmaf(s, dy, ay);
            }
        } else {                            // BB diag
            const float bx = me.x, by = me.y, hx = me.z, hy = me.w;
            #pragma unroll 7
            for (int k = 1; k < 64; ++k) {
                const float4 q = Jd[w][lane + k];
                const float dax = bx - q.x, day = by - q.y;
                const float ovx = (hx + q.z) - fabsf(dax);
                const float ovy = (hy + q.w) - fabsf(day);
                const bool hit = fminf(ovx, ovy) > 0.0f;
                const bool ux  = ovx <= ovy;
                ax += (hit && ux)  ? copysignf(0.5f * ovx, dax) : 0.0f;
                ay += (hit && !ux) ? copysignf(0.5f * ovy, day) : 0.0f;
            }
        }
    }

    atomicAdd(&out[(((I << 6) + lane) << 1)],     ax);
    atomicAdd(&out[(((I << 6) + lane) << 1) + 1], ay);
}

extern "C" void kernel_launch(void* const* d_in, const int* in_sizes, int n_in,
                              void* d_out, int out_size, void* d_ws, size_t ws_size,
                              hipStream_t stream) {
    (void)n_in; (void)out_size; (void)ws_size;

    const float2* cpos  = (const float2*)d_in[0];
    const float*  crad  = (const float*) d_in[1];
    const float2* apos  = (const float2*)d_in[2];
    const float2* ahalf = (const float2*)d_in[3];

    const int Nc   = in_sizes[1];       // 4096
    const int Na   = in_sizes[2] / 2;   // 2048
    const int Ntot = Nc + Na;           // 6144 = 96 tiles of 64

    float4* P = (float4*)d_ws;

    prep<<<(Ntot + 255) / 256, 256, 0, stream>>>(cpos, crad, apos, ahalf,
                                                 P, (float2*)d_out, Nc, Ntot);

    const int tile_pairs = (96 * 97) / 2;       // 4656
    const int blocks = tile_pairs / 4;          // 1164
    collide<<<blocks, 256, 0, stream>>>(P, (float*)d_out, Nc);
}

// Round 12
// 76.064 us; speedup vs baseline: 3.5679x; 3.5679x over previous
//
#include <hip/hip_runtime.h>
#include <math.h>

#define EPS 1e-9f

__device__ __forceinline__ int tri_off(int I) { return I * (193 - I) / 2; }  // 96 tiles

// Symmetric tile-pair kernel, register-rotation scatter.
// Wave t handles unordered tile pair (I<=J) of 96 body tiles (64 bodies each;
// tiles 0..63 circles, 64..95 boxes). Lane l owns I-body l (accum ax,ay).
// J tile staged doubled in per-wave LDS (stride-1 ds_read_b128, conflict-free).
// Off-diagonal: at step m lane l computes pair (I-body l, J-body (l+m)&63),
// computes the force ON the J body (q-p orientation, verified in R11), adds it
// to a rotating register accumulator g, then rotates g one lane (__shfl,
// src=(lane+1)&63). After 64 add+rotate steps lane l holds J-body l's total.
// I side accumulates -f. Diagonal: pure gather k=1..63 (rotation never
// self-pairs) + base-position fold (each body is in exactly one diag tile).
// No LDS atomics, no raw cross-lane LDS RMW (R10/R11 failure modes).
__global__ __launch_bounds__(256)
void collide(const float2* __restrict__ cpos,
             const float*  __restrict__ crad,
             const float2* __restrict__ apos,
             const float2* __restrict__ ahalf,
             float* __restrict__ out,
             int Nc) {
    const int lane = threadIdx.x & 63;
    const int w    = threadIdx.x >> 6;
    const int t    = blockIdx.x * 4 + w;          // tile-pair id 0..4655 (uniform)

    // triangular decode t -> (I, J), I <= J  (37249 - 8t exact in f32)
    int I = (int)((193.0f - sqrtf((float)(37249 - 8 * t))) * 0.5f);
    while (tri_off(I + 1) <= t) ++I;
    while (tri_off(I) > t) --I;
    const int J = I + (t - tri_off(I));

    const int tileC  = Nc >> 6;                   // 64 circle tiles
    const bool bodyC = I < tileC;                 // uniform
    const bool partC = J < tileC;                 // uniform (I<=J: partC => bodyC)

    __shared__ float4 Jd[4][128];

    {   // stage J tile (doubled) straight from inputs; circle radius pre-halved
        const int j = (J << 6) + lane;
        float4 q;
        if (partC) {
            const float2 c = cpos[j];
            q = make_float4(c.x, c.y, 0.5f * crad[j], 0.0f);
        } else {
            const float2 a = apos[j - Nc];
            const float2 h = ahalf[j - Nc];
            q = make_float4(a.x, a.y, h.x, h.y);
        }
        Jd[w][lane]      = q;
        Jd[w][lane + 64] = q;
    }
    __syncthreads();

    const int i = (I << 6) + lane;
    float4 me;
    if (bodyC) {
        const float2 c = cpos[i];
        me = make_float4(c.x, c.y, 0.5f * crad[i], 0.0f);
    } else {
        const float2 a = apos[i - Nc];
        const float2 h = ahalf[i - Nc];
        me = make_float4(a.x, a.y, h.x, h.y);
    }

    float ax = 0.0f, ay = 0.0f;
    const int src = (lane + 1) & 63;              // rotation source lane

    if (I != J) {
        float gx = 0.0f, gy = 0.0f;               // rotating J-side accumulator
        if (partC) {                              // CC (both circle tiles)
            const float px = me.x, py = me.y, rih = me.z;
            #pragma unroll 4
            for (int m = 0; m < 64; ++m) {
                const float4 q = Jd[w][lane + m];
                const float dx = q.x - px, dy = q.y - py;        // q - p
                const float d2 = fmaf(dx, dx, dy * dy);
                const float r  = __builtin_amdgcn_rsqf(d2);
                const float s  = fmaxf(fmaf(rih + q.z, r, -0.5f), 0.0f);
                const float fx = s * dx, fy = s * dy;            // force on J body
                ax -= fx; ay -= fy;                              // equal & opposite on I
                gx += fx; gy += fy;
                gx = __shfl(gx, src, 64);                        // rotate accumulator
                gy = __shfl(gy, src, 64);
            }
        } else if (bodyC) {                       // CB: I circle tile, J box tile
            const float px = me.x, py = me.y, rih = me.z;
            #pragma unroll 4
            for (int m = 0; m < 64; ++m) {
                const float4 q = Jd[w][lane + m];
                const float rx = q.x - px, ry = q.y - py;        // box - circle
                const float cx = fminf(fmaxf(rx, -q.z), q.z);
                const float cy = fminf(fmaxf(ry, -q.w), q.w);
                const float dx = rx - cx, dy = ry - cy;          // = -(ref diff)
                const float d2 = fmaf(dx, dx, dy * dy);
                const float r  = __builtin_amdgcn_rsqf(d2);
                float s = fmaxf(fmaf(rih, r, -0.5f), 0.0f);
                s = (d2 > EPS) ? s : 0.0f;                       // center-inside-box guard
                const float fx = s * dx, fy = s * dy;            // force on box
                ax -= fx; ay -= fy;                              // push on circle
                gx += fx; gy += fy;
                gx = __shfl(gx, src, 64);
                gy = __shfl(gy, src, 64);
            }
        } else {                                  // BB (both box tiles)
            const float bx = me.x, by = me.y, hx = me.z, hy = me.w;
            #pragma unroll 4
            for (int m = 0; m < 64; ++m) {
                const float4 q = Jd[w][lane + m];
                const float dqx = q.x - bx, dqy = q.y - by;      // q - me
                const float ovx = (hx + q.z) - fabsf(dqx);
                const float ovy = (hy + q.w) - fabsf(dqy);
                const bool hit = fminf(ovx, ovy) > 0.0f;
                const bool ux  = ovx <= ovy;
                const float fx = (hit && ux)  ? copysignf(0.5f * ovx, dqx) : 0.0f;
                const float fy = (hit && !ux) ? copysignf(0.5f * ovy, dqy) : 0.0f;
                ax -= fx; ay -= fy;
                gx += fx; gy += fy;
                gx = __shfl(gx, src, 64);
                gy = __shfl(gy, src, 64);
            }
        }
        atomicAdd(&out[(((J << 6) + lane) << 1)],     gx);
        atomicAdd(&out[(((J << 6) + lane) << 1) + 1], gy);
    } else {
        // diagonal: gather k=1..63; fold base position here (unique per body)
        if (bodyC) {                              // CC diag
            const float px = me.x, py = me.y, rih = me.z;
            #pragma unroll 7
            for (int k = 1; k < 64; ++k) {
                const float4 q = Jd[w][lane + k];
                const float dx = px - q.x, dy = py - q.y;        // p - q (I side)
                const float d2 = fmaf(dx, dx, dy * dy);
                const float r  = __builtin_amdgcn_rsqf(d2);
                const float s  = fmaxf(fmaf(rih + q.z, r, -0.5f), 0.0f);
                ax = fmaf(s, dx, ax); ay = fmaf(s, dy, ay);
            }
        } else {                                  // BB diag
            const float bx = me.x, by = me.y, hx = me.z, hy = me.w;
            #pragma unroll 7
            for (int k = 1; k < 64; ++k) {
                const float4 q = Jd[w][lane + k];
                const float dax = bx - q.x, day = by - q.y;
                const float ovx = (hx + q.z) - fabsf(dax);
                const float ovy = (hy + q.w) - fabsf(day);
                const bool hit = fminf(ovx, ovy) > 0.0f;
                const bool ux  = ovx <= ovy;
                ax += (hit && ux)  ? copysignf(0.5f * ovx, dax) : 0.0f;
                ay += (hit && !ux) ? copysignf(0.5f * ovy, day) : 0.0f;
            }
        }
        ax += me.x; ay += me.y;                   // base position
    }

    atomicAdd(&out[(i << 1)],     ax);
    atomicAdd(&out[(i << 1) + 1], ay);
}

extern "C" void kernel_launch(void* const* d_in, const int* in_sizes, int n_in,
                              void* d_out, int out_size, void* d_ws, size_t ws_size,
                              hipStream_t stream) {
    (void)n_in; (void)d_ws; (void)ws_size;

    const float2* cpos  = (const float2*)d_in[0];
    const float*  crad  = (const float*) d_in[1];
    const float2* apos  = (const float2*)d_in[2];
    const float2* ahalf = (const float2*)d_in[3];

    const int Nc = in_sizes[1];       // 4096

    // out accumulates via atomics; zero it (small: ~48 KB)
    hipMemsetAsync(d_out, 0, (size_t)out_size * sizeof(float), stream);

    const int tile_pairs = (96 * 97) / 2;       // 4656
    const int blocks = tile_pairs / 4;          // 1164
    collide<<<blocks, 256, 0, stream>>>(cpos, crad, apos, ahalf, (float*)d_out, Nc);
}